// Round 3
// baseline (2420.859 us; speedup 1.0000x reference)
//
#include <hip/hip_runtime.h>
#include <stdint.h>

// SChunkTransformerEncoderLayer: B=16, L=2048, C=512, HEADS=4, DK=128,
// CHUNK=16, nW=128, SHIFT=8. fp32 I/O (per reference), bf16 internal
// activations, fp32 accumulation.
//
// Workspace layout (adaptive, graph-safe):
//   R0 @0    32MiB : xn_s (bf16)  -> xn2
//   R1 @32M  32MiB : q            -> att (in-place)
//   R2 @64M  32MiB : k            -> x1 (bf16)
//   R3 @96M  32MiB : v            -> h-quarter (small tier)
//   @128M          : h (128MiB, big tier) / h-half (64MiB, mid tier)

typedef unsigned short bfu;

union U8 { uint4 v; unsigned short s[8]; };
union F4 { float4 v; float f[4]; };

__device__ __forceinline__ float bf2f(unsigned short u) {
    union { uint32_t i; float f; } c; c.i = ((uint32_t)u) << 16; return c.f;
}
__device__ __forceinline__ unsigned short f2bf(float f) {
    union { float f; uint32_t i; } c; c.f = f;
    uint32_t x = c.i;
    return (unsigned short)((x + 0x7FFFu + ((x >> 16) & 1u)) >> 16);
}

// ---------------- LayerNorm kernels (one wave per 512-elem row) ----------------

// LN1 with cyclic shift fused: out[ms] = LN(x[b, (ls+8)%L]); fp32 in, bf16 out.
__global__ __launch_bounds__(64) void ln1_shift_kernel(
    const float* __restrict__ x, const float* __restrict__ g,
    const float* __restrict__ be, bfu* __restrict__ out)
{
    const int ms = blockIdx.x;
    const int b = ms >> 11;
    const int ls = ms & 2047;
    const int l = (ls + 8) & 2047;
    const int c0 = threadIdx.x << 3;
    const float* xp = x + ((((size_t)(b << 11)) + l) << 9) + c0;
    F4 f0, f1; f0.v = *(const float4*)xp; f1.v = *(const float4*)(xp + 4);
    float vv[8]; float s = 0.f, sq = 0.f;
#pragma unroll
    for (int j = 0; j < 4; ++j) { vv[j] = f0.f[j]; vv[4 + j] = f1.f[j]; }
#pragma unroll
    for (int j = 0; j < 8; ++j) { s += vv[j]; sq += vv[j] * vv[j]; }
#pragma unroll
    for (int o = 32; o > 0; o >>= 1) { s += __shfl_xor(s, o); sq += __shfl_xor(sq, o); }
    const float mean = s * (1.f / 512.f);
    float var = sq * (1.f / 512.f) - mean * mean;
    var = fmaxf(var, 0.f);
    const float rstd = rsqrtf(var + 1e-12f);
    F4 g0, g1v, b0, b1;
    g0.v = *(const float4*)(g + c0);  g1v.v = *(const float4*)(g + c0 + 4);
    b0.v = *(const float4*)(be + c0); b1.v = *(const float4*)(be + c0 + 4);
    U8 o8;
#pragma unroll
    for (int j = 0; j < 4; ++j) {
        o8.s[j]     = f2bf((vv[j]     - mean) * rstd * g0.f[j]  + b0.f[j]);
        o8.s[4 + j] = f2bf((vv[4 + j] - mean) * rstd * g1v.f[j] + b1.f[j]);
    }
    *(uint4*)(out + (((size_t)ms) << 9) + c0) = o8.v;
}

// LN2: bf16 in (x1), bf16 out.
__global__ __launch_bounds__(64) void ln2_kernel(
    const bfu* __restrict__ x1, const float* __restrict__ g,
    const float* __restrict__ be, bfu* __restrict__ out)
{
    const int ms = blockIdx.x;
    const int c0 = threadIdx.x << 3;
    U8 u; u.v = *(const uint4*)(x1 + (((size_t)ms) << 9) + c0);
    float vv[8]; float s = 0.f, sq = 0.f;
#pragma unroll
    for (int j = 0; j < 8; ++j) { float f = bf2f(u.s[j]); vv[j] = f; s += f; sq += f * f; }
#pragma unroll
    for (int o = 32; o > 0; o >>= 1) { s += __shfl_xor(s, o); sq += __shfl_xor(sq, o); }
    const float mean = s * (1.f / 512.f);
    float var = sq * (1.f / 512.f) - mean * mean;
    var = fmaxf(var, 0.f);
    const float rstd = rsqrtf(var + 1e-12f);
    F4 g0, g1v, b0, b1;
    g0.v = *(const float4*)(g + c0);  g1v.v = *(const float4*)(g + c0 + 4);
    b0.v = *(const float4*)(be + c0); b1.v = *(const float4*)(be + c0 + 4);
    U8 o8;
#pragma unroll
    for (int j = 0; j < 4; ++j) {
        o8.s[j]     = f2bf((vv[j]     - mean) * rstd * g0.f[j]  + b0.f[j]);
        o8.s[4 + j] = f2bf((vv[4 + j] - mean) * rstd * g1v.f[j] + b1.f[j]);
    }
    *(uint4*)(out + (((size_t)ms) << 9) + c0) = o8.v;
}

// ---------------- Tiled GEMM: Y = X(MxK,bf16) @ W(KxN,fp32,ld=ldw) + bias ----------------
// 128x128 tile, BK=16, 256 threads, 8x8 microtile, fp32 accum.
// EPI 0: Ob = bf16(Y+bias)                       (q/k/v)
// EPI 1: Ob = bf16(relu(Y+bias))                 (h)
// EPI 2: Ob[unshifted] = bf16(x[uns] + (Y+bias)*mp[l])   (x1; xres fp32)
// EPI 3: Ofl = prevb(bf16 x1) + Y + bias         (out fp32)
// EPI 4: Ofl = prevf(fp32 out) + Y               (out accum, no bias)

template<int EPI>
__global__ __launch_bounds__(256) void gemm_k(
    const bfu* __restrict__ X, const float* __restrict__ W,
    const float* __restrict__ bias,
    bfu* Ob, float* Ofl,
    const float* __restrict__ xres,
    const bfu* __restrict__ prevb, const float* prevf,
    const float* __restrict__ maskpad,
    int M, int N, int K, int ldw)
{
    __shared__ float As[16][128];
    __shared__ float Bs[16][128];
    const int t = threadIdx.x;
    const int row0 = blockIdx.y << 7;
    const int col0 = blockIdx.x << 7;

    const int a_m = t >> 1;            // 0..127
    const int a_k = (t & 1) << 3;      // 0 or 8
    const int b_k = t >> 4;            // 0..15
    const int b_n = (t & 15) << 3;     // 0..120

    const bfu* aptr = X + (size_t)(row0 + a_m) * K + a_k;
    const float* bptr = W + (size_t)b_k * ldw + col0 + b_n;

    float acc[8][8];
#pragma unroll
    for (int i = 0; i < 8; ++i)
#pragma unroll
        for (int j = 0; j < 8; ++j) acc[i][j] = 0.f;

    const int tm = (t >> 4) << 3;
    const int tn = (t & 15) << 3;

    for (int k0 = 0; k0 < K; k0 += 16) {
        U8 ua;
        F4 w0, w1;
        ua.v = *(const uint4*)aptr;
        w0.v = *(const float4*)bptr;
        w1.v = *(const float4*)(bptr + 4);
        aptr += 16;
        bptr += (size_t)16 * ldw;
        __syncthreads();
#pragma unroll
        for (int j = 0; j < 8; ++j) As[a_k + j][a_m] = bf2f(ua.s[j]);
#pragma unroll
        for (int j = 0; j < 4; ++j) {
            Bs[b_k][b_n + j] = w0.f[j];
            Bs[b_k][b_n + 4 + j] = w1.f[j];
        }
        __syncthreads();
#pragma unroll
        for (int kk = 0; kk < 16; ++kk) {
            float a[8], b[8];
#pragma unroll
            for (int i = 0; i < 8; ++i) a[i] = As[kk][tm + i];
#pragma unroll
            for (int j = 0; j < 8; ++j) b[j] = Bs[kk][tn + j];
#pragma unroll
            for (int i = 0; i < 8; ++i)
#pragma unroll
                for (int j = 0; j < 8; ++j) acc[i][j] += a[i] * b[j];
        }
    }

    float bsv[8];
#pragma unroll
    for (int j = 0; j < 8; ++j) bsv[j] = (EPI == 4) ? 0.f : bias[col0 + tn + j];

#pragma unroll
    for (int i = 0; i < 8; ++i) {
        const int row = row0 + tm + i;
        if (EPI == 0 || EPI == 1) {
            U8 o8;
#pragma unroll
            for (int j = 0; j < 8; ++j) {
                float y = acc[i][j] + bsv[j];
                if (EPI == 1) y = fmaxf(y, 0.f);
                o8.s[j] = f2bf(y);
            }
            *(uint4*)(Ob + (size_t)row * N + col0 + tn) = o8.v;
        } else if (EPI == 2) {
            const int bb = row >> 11;
            const int ls = row & 2047;
            const int l = (ls + 8) & 2047;   // reverse shift
            const float mp = maskpad[(bb << 11) + l];
            const size_t dst = ((size_t)(bb << 11) + l) * (size_t)N + col0 + tn;
            F4 x0, x1v;
            x0.v = *(const float4*)(xres + dst);
            x1v.v = *(const float4*)(xres + dst + 4);
            U8 o8;
#pragma unroll
            for (int j = 0; j < 4; ++j) {
                o8.s[j]     = f2bf(x0.f[j]  + (acc[i][j]     + bsv[j])     * mp);
                o8.s[4 + j] = f2bf(x1v.f[j] + (acc[i][4 + j] + bsv[4 + j]) * mp);
            }
            *(uint4*)(Ob + dst) = o8.v;
        } else if (EPI == 3) {
            const size_t dst = (size_t)row * N + col0 + tn;
            F4 o0, o1;
#pragma unroll
            for (int j = 0; j < 4; ++j) {
                o0.f[j] = bf2f(prevb[dst + j])     + acc[i][j]     + bsv[j];
                o1.f[j] = bf2f(prevb[dst + 4 + j]) + acc[i][4 + j] + bsv[4 + j];
            }
            *(float4*)(Ofl + dst) = o0.v;
            *(float4*)(Ofl + dst + 4) = o1.v;
        } else { // EPI 4
            const size_t dst = (size_t)row * N + col0 + tn;
            F4 p0, p1, o0, o1;
            p0.v = *(const float4*)(prevf + dst);
            p1.v = *(const float4*)(prevf + dst + 4);
#pragma unroll
            for (int j = 0; j < 4; ++j) {
                o0.f[j] = p0.f[j] + acc[i][j];
                o1.f[j] = p1.f[j] + acc[i][4 + j];
            }
            *(float4*)(Ofl + dst) = o0.v;
            *(float4*)(Ofl + dst + 4) = o1.v;
        }
    }
}

// ---------------- Windowed attention: one block per (window, head) ----------------

__global__ __launch_bounds__(256) void attn_kernel(
    const bfu* __restrict__ q, const bfu* __restrict__ k,
    const bfu* __restrict__ v, const float* __restrict__ mpad,
    bfu* __restrict__ out)   // may alias q (block-local in-place)
{
    __shared__ float qs[16][129];
    __shared__ float ks[16][129];
    __shared__ float vs[16][129];
    __shared__ float ps[16][17];
    const int t = threadIdx.x;
    const int wg = blockIdx.x;          // b*128 + w
    const int h = blockIdx.y;
    const int b = wg >> 7;
    const int w = wg & 127;
    const int li = t >> 4;              // 0..15
    const int d0 = (t & 15) << 3;       // 0..120
    const size_t base = (((size_t)wg << 4) + li) * 512 + (h << 7) + d0;
    U8 uq, uk, uv;
    uq.v = *(const uint4*)(q + base);
    uk.v = *(const uint4*)(k + base);
    uv.v = *(const uint4*)(v + base);
#pragma unroll
    for (int j = 0; j < 8; ++j) {
        qs[li][d0 + j] = bf2f(uq.s[j]);
        ks[li][d0 + j] = bf2f(uk.s[j]);
        vs[li][d0 + j] = bf2f(uv.s[j]);
    }
    __syncthreads();
    const int qi = li, ki = t & 15;
    float s = 0.f;
#pragma unroll 8
    for (int d = 0; d < 128; ++d) s += qs[qi][d] * ks[ki][d];
    s *= 0.088388347648318447f;         // 1/sqrt(128)
    // swin shift mask: windows 0..126: rows 0..6 x cols 8..15; window 127: rows/cols 8..15
    const bool lastw = (w == 127);
    if (lastw ? (qi >= 8 && ki >= 8) : (qi < 7 && ki >= 8)) s -= 100.f;
    // key padding mask (shifted)
    const int lkey = ((w << 4) + ki + 8) & 2047;
    const bool valid = mpad[(b << 11) + lkey] > 0.f;
    if (!valid) s = -1e30f;
    float mx = s;
#pragma unroll
    for (int o = 8; o > 0; o >>= 1) mx = fmaxf(mx, __shfl_xor(mx, o, 16));
    float e = __expf(s - mx);
    float sum = e;
#pragma unroll
    for (int o = 8; o > 0; o >>= 1) sum += __shfl_xor(sum, o, 16);
    float p = e / sum;
    if (!valid) p = 0.f;
    ps[qi][ki] = p;
    __syncthreads();
    float o_[8];
#pragma unroll
    for (int j = 0; j < 8; ++j) o_[j] = 0.f;
#pragma unroll
    for (int kk = 0; kk < 16; ++kk) {
        const float pw = ps[li][kk];
#pragma unroll
        for (int j = 0; j < 8; ++j) o_[j] += pw * vs[kk][d0 + j];
    }
    U8 o8;
#pragma unroll
    for (int j = 0; j < 8; ++j) o8.s[j] = f2bf(o_[j]);
    *(uint4*)(out + base) = o8.v;
}

// ---------------- Launch ----------------

extern "C" void kernel_launch(void* const* d_in, const int* in_sizes, int n_in,
                              void* d_out, int out_size, void* d_ws, size_t ws_size,
                              hipStream_t stream)
{
    const float* x    = (const float*)d_in[0];
    // d_in[1] mask: unused; d_in[2] pos_emb: zeros, unused
    const float* mpad = (const float*)d_in[3];
    const float* Wq = (const float*)d_in[4];  const float* bq = (const float*)d_in[5];
    const float* Wk = (const float*)d_in[6];  const float* bk = (const float*)d_in[7];
    const float* Wv = (const float*)d_in[8];  const float* bv = (const float*)d_in[9];
    const float* Wo = (const float*)d_in[10]; const float* bo = (const float*)d_in[11];
    const float* g1 = (const float*)d_in[12]; const float* be1 = (const float*)d_in[13];
    const float* g2 = (const float*)d_in[14]; const float* be2 = (const float*)d_in[15];
    const float* W1 = (const float*)d_in[16]; const float* bf1 = (const float*)d_in[17];
    const float* W2 = (const float*)d_in[18]; const float* bf2 = (const float*)d_in[19];
    float* out = (float*)d_out;

    char* p = (char*)d_ws;
    const size_t MB = (size_t)1 << 20;
    bfu* xn_s = (bfu*)p;               // R0; later xn2
    bfu* qb   = (bfu*)(p + 32 * MB);   // R1; later att (in-place)
    bfu* kb   = (bfu*)(p + 64 * MB);   // R2; later x1 (bf16)
    bfu* vb   = (bfu*)(p + 96 * MB);   // R3; later h-quarter (small tier)
    bfu* hb   = (bfu*)(p + 128 * MB);  // big: h 128MiB; mid: h-half 64MiB
    bfu* att  = qb;
    bfu* x1   = kb;
    bfu* xn2  = xn_s;

    const int M = 32768;
    dim3 blk(256);
    dim3 g512(4, 256);
    dim3 g1024(8, 256);
    dim3 g2048(16, 256);

    ln1_shift_kernel<<<32768, 64, 0, stream>>>(x, g1, be1, xn_s);

    gemm_k<0><<<g512, blk, 0, stream>>>(xn_s, Wq, bq, qb, nullptr, nullptr, nullptr, nullptr, nullptr, M, 512, 512, 512);
    gemm_k<0><<<g512, blk, 0, stream>>>(xn_s, Wk, bk, kb, nullptr, nullptr, nullptr, nullptr, nullptr, M, 512, 512, 512);
    gemm_k<0><<<g512, blk, 0, stream>>>(xn_s, Wv, bv, vb, nullptr, nullptr, nullptr, nullptr, nullptr, M, 512, 512, 512);

    attn_kernel<<<dim3(2048, 4), blk, 0, stream>>>(qb, kb, vb, mpad, att);

    gemm_k<2><<<g512, blk, 0, stream>>>(att, Wo, bo, x1, nullptr, x, nullptr, nullptr, mpad, M, 512, 512, 512);

    ln2_kernel<<<32768, 64, 0, stream>>>(x1, g2, be2, xn2);

    if (ws_size >= 256 * MB) {
        gemm_k<1><<<g2048, blk, 0, stream>>>(xn2, W1, bf1, hb, nullptr, nullptr, nullptr, nullptr, nullptr, M, 2048, 512, 2048);
        gemm_k<3><<<g512, blk, 0, stream>>>(hb, W2, bf2, nullptr, out, nullptr, x1, nullptr, nullptr, M, 512, 2048, 512);
    } else if (ws_size >= 192 * MB) {
        gemm_k<1><<<g1024, blk, 0, stream>>>(xn2, W1, bf1, hb, nullptr, nullptr, nullptr, nullptr, nullptr, M, 1024, 512, 2048);
        gemm_k<3><<<g512, blk, 0, stream>>>(hb, W2, bf2, nullptr, out, nullptr, x1, nullptr, nullptr, M, 512, 1024, 512);
        gemm_k<1><<<g1024, blk, 0, stream>>>(xn2, W1 + 1024, bf1 + 1024, hb, nullptr, nullptr, nullptr, nullptr, nullptr, M, 1024, 512, 2048);
        gemm_k<4><<<g512, blk, 0, stream>>>(hb, W2 + (size_t)1024 * 512, nullptr, nullptr, out, nullptr, nullptr, out, nullptr, M, 512, 1024, 512);
    } else {
        // four 512-wide hidden passes; h-quarter (32 MiB) at R3 (v dead)
        for (int s = 0; s < 4; ++s) {
            gemm_k<1><<<g512, blk, 0, stream>>>(xn2, W1 + s * 512, bf1 + s * 512, vb, nullptr, nullptr, nullptr, nullptr, nullptr, M, 512, 512, 2048);
            if (s == 0)
                gemm_k<3><<<g512, blk, 0, stream>>>(vb, W2, bf2, nullptr, out, nullptr, x1, nullptr, nullptr, M, 512, 512, 512);
            else
                gemm_k<4><<<g512, blk, 0, stream>>>(vb, W2 + (size_t)s * 512 * 512, nullptr, nullptr, out, nullptr, nullptr, out, nullptr, M, 512, 512, 512);
        }
    }
}

// Round 4
// 767.656 us; speedup vs baseline: 3.1536x; 3.1536x over previous
//
#include <hip/hip_runtime.h>
#include <stdint.h>

// SChunkTransformerEncoderLayer: B=16, L=2048, C=512, HEADS=4, DK=128,
// CHUNK=16, nW=128, SHIFT=8. fp32 I/O, bf16 internal, fp32 accum.
// GEMMs on MFMA 16x16x32 bf16 (m97-style: 128x128 tile, BK=32,
// global_load_lds width-16, chunk-major LDS, 4x4 frags/wave).
//
// Workspace (ws_size >= 256 MiB, proven by R3 big-tier run):
//   @0    32M : xn_s -> xn2                (bf16)
//   @32M  32M : q -> att -> {W1t,W2t 4MiB} (bf16)
//   @64M  32M : k -> x1                    (bf16)
//   @96M  32M : v                          (bf16)
//   @128M 128M: {Wqt..Wot 2MiB, dead at FFN} then h (bf16)

typedef unsigned short bfu;

using bf16x8 = __attribute__((ext_vector_type(8))) __bf16;
using f32x4  = __attribute__((ext_vector_type(4))) float;

union U8 { uint4 v; unsigned short s[8]; };
union F4 { float4 v; float f[4]; };
union ABFrag { uint4 u; bf16x8 f; };

__device__ __forceinline__ float bf2f(unsigned short u) {
    union { uint32_t i; float f; } c; c.i = ((uint32_t)u) << 16; return c.f;
}
__device__ __forceinline__ unsigned short f2bf(float f) {
    union { float f; uint32_t i; } c; c.f = f;
    uint32_t x = c.i;
    return (unsigned short)((x + 0x7FFFu + ((x >> 16) & 1u)) >> 16);
}

#define GLDS16(gp, lp)                                                        \
    __builtin_amdgcn_global_load_lds(                                         \
        (__attribute__((address_space(1))) void*)(gp),                        \
        (__attribute__((address_space(3))) void*)(lp), 16, 0, 0)

// ---------------- weight convert+transpose: Wt[n][k] = bf16(W[k][n]) --------

__global__ __launch_bounds__(256) void wconv_kernel(
    const float* __restrict__ W, bfu* __restrict__ Wt, int K, int N)
{
    __shared__ float t[32][33];
    const int bn = blockIdx.x << 5;
    const int bk = blockIdx.y << 5;
    const int tx = threadIdx.x & 31, ty = threadIdx.x >> 5;   // 8 rows/pass
#pragma unroll
    for (int i = 0; i < 32; i += 8)
        t[ty + i][tx] = W[(size_t)(bk + ty + i) * N + bn + tx];
    __syncthreads();
#pragma unroll
    for (int i = 0; i < 32; i += 8)
        Wt[(size_t)(bn + ty + i) * K + bk + tx] = f2bf(t[tx][ty + i]);
}

// ---------------- LayerNorm kernels ----------------

__global__ __launch_bounds__(64) void ln1_shift_kernel(
    const float* __restrict__ x, const float* __restrict__ g,
    const float* __restrict__ be, bfu* __restrict__ out)
{
    const int ms = blockIdx.x;
    const int b = ms >> 11;
    const int ls = ms & 2047;
    const int l = (ls + 8) & 2047;
    const int c0 = threadIdx.x << 3;
    const float* xp = x + ((((size_t)(b << 11)) + l) << 9) + c0;
    F4 f0, f1; f0.v = *(const float4*)xp; f1.v = *(const float4*)(xp + 4);
    float vv[8]; float s = 0.f, sq = 0.f;
#pragma unroll
    for (int j = 0; j < 4; ++j) { vv[j] = f0.f[j]; vv[4 + j] = f1.f[j]; }
#pragma unroll
    for (int j = 0; j < 8; ++j) { s += vv[j]; sq += vv[j] * vv[j]; }
#pragma unroll
    for (int o = 32; o > 0; o >>= 1) { s += __shfl_xor(s, o); sq += __shfl_xor(sq, o); }
    const float mean = s * (1.f / 512.f);
    float var = sq * (1.f / 512.f) - mean * mean;
    var = fmaxf(var, 0.f);
    const float rstd = rsqrtf(var + 1e-12f);
    F4 g0, g1v, b0, b1;
    g0.v = *(const float4*)(g + c0);  g1v.v = *(const float4*)(g + c0 + 4);
    b0.v = *(const float4*)(be + c0); b1.v = *(const float4*)(be + c0 + 4);
    U8 o8;
#pragma unroll
    for (int j = 0; j < 4; ++j) {
        o8.s[j]     = f2bf((vv[j]     - mean) * rstd * g0.f[j]  + b0.f[j]);
        o8.s[4 + j] = f2bf((vv[4 + j] - mean) * rstd * g1v.f[j] + b1.f[j]);
    }
    *(uint4*)(out + (((size_t)ms) << 9) + c0) = o8.v;
}

__global__ __launch_bounds__(64) void ln2_kernel(
    const bfu* __restrict__ x1, const float* __restrict__ g,
    const float* __restrict__ be, bfu* __restrict__ out)
{
    const int ms = blockIdx.x;
    const int c0 = threadIdx.x << 3;
    U8 u; u.v = *(const uint4*)(x1 + (((size_t)ms) << 9) + c0);
    float vv[8]; float s = 0.f, sq = 0.f;
#pragma unroll
    for (int j = 0; j < 8; ++j) { float f = bf2f(u.s[j]); vv[j] = f; s += f; sq += f * f; }
#pragma unroll
    for (int o = 32; o > 0; o >>= 1) { s += __shfl_xor(s, o); sq += __shfl_xor(sq, o); }
    const float mean = s * (1.f / 512.f);
    float var = sq * (1.f / 512.f) - mean * mean;
    var = fmaxf(var, 0.f);
    const float rstd = rsqrtf(var + 1e-12f);
    F4 g0, g1v, b0, b1;
    g0.v = *(const float4*)(g + c0);  g1v.v = *(const float4*)(g + c0 + 4);
    b0.v = *(const float4*)(be + c0); b1.v = *(const float4*)(be + c0 + 4);
    U8 o8;
#pragma unroll
    for (int j = 0; j < 4; ++j) {
        o8.s[j]     = f2bf((vv[j]     - mean) * rstd * g0.f[j]  + b0.f[j]);
        o8.s[4 + j] = f2bf((vv[4 + j] - mean) * rstd * g1v.f[j] + b1.f[j]);
    }
    *(uint4*)(out + (((size_t)ms) << 9) + c0) = o8.v;
}

// ---------------- MFMA GEMM: Y = X(MxK bf16) @ Wt^T(N x K bf16) + bias ------
// 128x128 tile, BK=32, 256 thr (4 waves, 2x2), wave tile 64x64 = 4x4 MFMAs.
// LDS chunk layout: chunk(q=0..3, idx=0..127) = 8 bf16 (16B) at (q*128+idx)*16B.
//   A chunk(q,m) = X[row0+m][k0+q*8 .. +8);  B chunk(q,n) = Wt[col0+n][k0+q*8..).
// Frag reads: lane(l15,q): A[m=l15][k=q*8+j] -> ds_read_b128, 2-way conflict max.
// EPI 0: Ob=bf16(Y+b)   1: Ob=bf16(relu(Y+b))
// EPI 2: Ob[unshift]=bf16(xres + (Y+b)*mp)   3: Ofl = bf2f(prevb) + Y + b

template<int EPI>
__global__ __launch_bounds__(256) void mgemm(
    const bfu* __restrict__ X, const bfu* __restrict__ Wt,
    const float* __restrict__ bias,
    bfu* Ob, float* Ofl,
    const float* __restrict__ xres, const bfu* __restrict__ prevb,
    const float* __restrict__ maskpad,
    int M, int N, int K)
{
    __shared__ bfu As[4096];   // 8 KiB
    __shared__ bfu Bs[4096];   // 8 KiB
    const int t = threadIdx.x;
    const int lane = t & 63;
    const int w = t >> 6;
    const int wm = w >> 1, wn = w & 1;
    const int row0 = blockIdx.y << 7;
    const int col0 = blockIdx.x << 7;
    const int q = lane >> 4, l15 = lane & 15;

    // staging: wave w stages k-quad w for all 128 rows/cols (2 issues of 64)
    const bfu* ga0 = X  + (size_t)(row0 + lane) * K + (w << 3);
    const bfu* ga1 = X  + (size_t)(row0 + 64 + lane) * K + (w << 3);
    const bfu* gb0 = Wt + (size_t)(col0 + lane) * K + (w << 3);
    const bfu* gb1 = Wt + (size_t)(col0 + 64 + lane) * K + (w << 3);
    bfu* lA0 = As + (w << 10);
    bfu* lA1 = As + (w << 10) + 512;
    bfu* lB0 = Bs + (w << 10);
    bfu* lB1 = Bs + (w << 10) + 512;

    f32x4 acc[4][4] = {};

    for (int k0 = 0; k0 < K; k0 += 32) {
        __syncthreads();
        GLDS16(ga0 + k0, lA0);
        GLDS16(ga1 + k0, lA1);
        GLDS16(gb0 + k0, lB0);
        GLDS16(gb1 + k0, lB1);
        __syncthreads();
        ABFrag af[4], bfr[4];
#pragma unroll
        for (int i = 0; i < 4; ++i)
            af[i].u = *(const uint4*)(As + (((q << 7) + (wm << 6) + (i << 4) + l15) << 3));
#pragma unroll
        for (int j = 0; j < 4; ++j)
            bfr[j].u = *(const uint4*)(Bs + (((q << 7) + (wn << 6) + (j << 4) + l15) << 3));
#pragma unroll
        for (int i = 0; i < 4; ++i)
#pragma unroll
            for (int j = 0; j < 4; ++j)
                acc[i][j] = __builtin_amdgcn_mfma_f32_16x16x32_bf16(
                    af[i].f, bfr[j].f, acc[i][j], 0, 0, 0);
    }

    float bsv[4];
    int colv[4];
#pragma unroll
    for (int j = 0; j < 4; ++j) {
        colv[j] = col0 + (wn << 6) + (j << 4) + l15;
        bsv[j] = bias[colv[j]];
    }

#pragma unroll
    for (int i = 0; i < 4; ++i) {
        const int rbase = row0 + (wm << 6) + (i << 4) + (q << 2);
#pragma unroll
        for (int r = 0; r < 4; ++r) {
            const int row = rbase + r;
            if (EPI == 0 || EPI == 1) {
#pragma unroll
                for (int j = 0; j < 4; ++j) {
                    float y = acc[i][j][r] + bsv[j];
                    if (EPI == 1) y = fmaxf(y, 0.f);
                    Ob[(size_t)row * N + colv[j]] = f2bf(y);
                }
            } else if (EPI == 2) {
                const int bb = row >> 11;
                const int ls = row & 2047;
                const int l = (ls + 8) & 2047;       // reverse shift
                const float mp = maskpad[(bb << 11) + l];
                const size_t rb = ((size_t)(bb << 11) + l) * (size_t)N;
#pragma unroll
                for (int j = 0; j < 4; ++j) {
                    const size_t dst = rb + colv[j];
                    Ob[dst] = f2bf(xres[dst] + (acc[i][j][r] + bsv[j]) * mp);
                }
            } else { // EPI 3
                const size_t rb = (size_t)row * N;
#pragma unroll
                for (int j = 0; j < 4; ++j) {
                    const size_t dst = rb + colv[j];
                    Ofl[dst] = bf2f(prevb[dst]) + acc[i][j][r] + bsv[j];
                }
            }
        }
    }
}

// ---------------- Windowed attention: one block per (window, head) ----------

__global__ __launch_bounds__(256) void attn_kernel(
    const bfu* __restrict__ q, const bfu* __restrict__ k,
    const bfu* __restrict__ v, const float* __restrict__ mpad,
    bfu* __restrict__ out)
{
    __shared__ float qs[16][129];
    __shared__ float ks[16][129];
    __shared__ float vs[16][129];
    __shared__ float ps[16][17];
    const int t = threadIdx.x;
    const int wg = blockIdx.x;
    const int h = blockIdx.y;
    const int b = wg >> 7;
    const int w = wg & 127;
    const int li = t >> 4;
    const int d0 = (t & 15) << 3;
    const size_t base = (((size_t)wg << 4) + li) * 512 + (h << 7) + d0;
    U8 uq, uk, uv;
    uq.v = *(const uint4*)(q + base);
    uk.v = *(const uint4*)(k + base);
    uv.v = *(const uint4*)(v + base);
#pragma unroll
    for (int j = 0; j < 8; ++j) {
        qs[li][d0 + j] = bf2f(uq.s[j]);
        ks[li][d0 + j] = bf2f(uk.s[j]);
        vs[li][d0 + j] = bf2f(uv.s[j]);
    }
    __syncthreads();
    const int qi = li, ki = t & 15;
    float s = 0.f;
#pragma unroll 8
    for (int d = 0; d < 128; ++d) s += qs[qi][d] * ks[ki][d];
    s *= 0.088388347648318447f;
    const bool lastw = (w == 127);
    if (lastw ? (qi >= 8 && ki >= 8) : (qi < 7 && ki >= 8)) s -= 100.f;
    const int lkey = ((w << 4) + ki + 8) & 2047;
    const bool valid = mpad[(b << 11) + lkey] > 0.f;
    if (!valid) s = -1e30f;
    float mx = s;
#pragma unroll
    for (int o = 8; o > 0; o >>= 1) mx = fmaxf(mx, __shfl_xor(mx, o, 16));
    float e = __expf(s - mx);
    float sum = e;
#pragma unroll
    for (int o = 8; o > 0; o >>= 1) sum += __shfl_xor(sum, o, 16);
    float p = e / sum;
    if (!valid) p = 0.f;
    ps[qi][ki] = p;
    __syncthreads();
    float o_[8];
#pragma unroll
    for (int j = 0; j < 8; ++j) o_[j] = 0.f;
#pragma unroll
    for (int kk = 0; kk < 16; ++kk) {
        const float pw = ps[li][kk];
#pragma unroll
        for (int j = 0; j < 8; ++j) o_[j] += pw * vs[kk][d0 + j];
    }
    U8 o8;
#pragma unroll
    for (int j = 0; j < 8; ++j) o8.s[j] = f2bf(o_[j]);
    *(uint4*)(out + base) = o8.v;
}

// ---------------- Launch ----------------

extern "C" void kernel_launch(void* const* d_in, const int* in_sizes, int n_in,
                              void* d_out, int out_size, void* d_ws, size_t ws_size,
                              hipStream_t stream)
{
    const float* x    = (const float*)d_in[0];
    const float* mpad = (const float*)d_in[3];
    const float* Wq = (const float*)d_in[4];  const float* bq = (const float*)d_in[5];
    const float* Wk = (const float*)d_in[6];  const float* bk = (const float*)d_in[7];
    const float* Wv = (const float*)d_in[8];  const float* bv = (const float*)d_in[9];
    const float* Wo = (const float*)d_in[10]; const float* bo = (const float*)d_in[11];
    const float* g1 = (const float*)d_in[12]; const float* be1 = (const float*)d_in[13];
    const float* g2 = (const float*)d_in[14]; const float* be2 = (const float*)d_in[15];
    const float* W1 = (const float*)d_in[16]; const float* bf1 = (const float*)d_in[17];
    const float* W2 = (const float*)d_in[18]; const float* bf2 = (const float*)d_in[19];
    float* out = (float*)d_out;

    char* p = (char*)d_ws;
    const size_t MB = (size_t)1 << 20;
    bfu* xn_s = (bfu*)p;               // @0   ; later xn2
    bfu* qb   = (bfu*)(p + 32 * MB);   // @32M ; later att, later W1t/W2t
    bfu* kb   = (bfu*)(p + 64 * MB);   // @64M ; later x1
    bfu* vb   = (bfu*)(p + 96 * MB);   // @96M
    bfu* hreg = (bfu*)(p + 128 * MB);  // @128M; Wqt..Wot head, later h
    bfu* att  = qb;
    bfu* x1   = kb;
    bfu* xn2  = xn_s;

    bfu* Wqt = hreg;                   // 4 x 256K elems = 2 MiB
    bfu* Wkt = hreg + 262144;
    bfu* Wvt = hreg + 2 * 262144;
    bfu* Wot = hreg + 3 * 262144;
    bfu* W1t = qb;                     // 2 MiB (after att dead)
    bfu* W2t = qb + 1048576;           // 2 MiB

    const int M = 32768;
    dim3 blk(256);
    dim3 gw512(16, 16);

    // convert QKV/O weights (needed before h overwrites them at FFN)
    wconv_kernel<<<gw512, blk, 0, stream>>>(Wq, Wqt, 512, 512);
    wconv_kernel<<<gw512, blk, 0, stream>>>(Wk, Wkt, 512, 512);
    wconv_kernel<<<gw512, blk, 0, stream>>>(Wv, Wvt, 512, 512);
    wconv_kernel<<<gw512, blk, 0, stream>>>(Wo, Wot, 512, 512);

    ln1_shift_kernel<<<32768, 64, 0, stream>>>(x, g1, be1, xn_s);

    mgemm<0><<<dim3(4, 256), blk, 0, stream>>>(xn_s, Wqt, bq, qb, nullptr, nullptr, nullptr, nullptr, M, 512, 512);
    mgemm<0><<<dim3(4, 256), blk, 0, stream>>>(xn_s, Wkt, bk, kb, nullptr, nullptr, nullptr, nullptr, M, 512, 512);
    mgemm<0><<<dim3(4, 256), blk, 0, stream>>>(xn_s, Wvt, bv, vb, nullptr, nullptr, nullptr, nullptr, M, 512, 512);

    attn_kernel<<<dim3(2048, 4), blk, 0, stream>>>(qb, kb, vb, mpad, att);

    mgemm<2><<<dim3(4, 256), blk, 0, stream>>>(att, Wot, bo, x1, nullptr, x, nullptr, mpad, M, 512, 512);

    // att region now dead -> stage FFN weights there
    wconv_kernel<<<dim3(64, 16), blk, 0, stream>>>(W1, W1t, 512, 2048);
    wconv_kernel<<<dim3(16, 64), blk, 0, stream>>>(W2, W2t, 2048, 512);

    ln2_kernel<<<32768, 64, 0, stream>>>(x1, g2, be2, xn2);

    mgemm<1><<<dim3(16, 256), blk, 0, stream>>>(xn2, W1t, bf1, hreg, nullptr, nullptr, nullptr, nullptr, M, 2048, 512);
    mgemm<3><<<dim3(4, 256), blk, 0, stream>>>(hreg, W2t, bf2, nullptr, out, nullptr, x1, nullptr, M, 512, 2048);
}

// Round 5
// 629.122 us; speedup vs baseline: 3.8480x; 1.2202x over previous
//
#include <hip/hip_runtime.h>
#include <stdint.h>

// SChunkTransformerEncoderLayer: B=16, L=2048, C=512, HEADS=4, DK=128,
// CHUNK=16, nW=128, SHIFT=8. fp32 I/O, bf16 internal, fp32 accum.
// MFMA 16x16x32 bf16 GEMMs, m97-style coalesced global_load_lds staging.
//
// Workspace (256 MiB, confirmed by R3/R4):
//   @0    : xn_s (32M)  -> att (32M)
//   @32M  : qkv (96M, stride 1536) -> x1@32M / W1t@64M / W2t@66M / xn2@96M
//   @128M : Wqkvt(1.5M)+Wot(0.5M)+bqkv(6K) -> h (128M)

typedef unsigned short bfu;

using bf16x8 = __attribute__((ext_vector_type(8))) __bf16;
using f32x4  = __attribute__((ext_vector_type(4))) float;

union U8 { uint4 v; unsigned short s[8]; };
union F4 { float4 v; float f[4]; };
union ABFrag { uint4 u; bf16x8 f; };

__device__ __forceinline__ float bf2f(unsigned short u) {
    union { uint32_t i; float f; } c; c.i = ((uint32_t)u) << 16; return c.f;
}
__device__ __forceinline__ unsigned short f2bf(float f) {
    union { float f; uint32_t i; } c; c.f = f;
    uint32_t x = c.i;
    return (unsigned short)((x + 0x7FFFu + ((x >> 16) & 1u)) >> 16);
}
__device__ __forceinline__ uint4 pack8(float4 a, float4 b) {
    U8 o;
    o.s[0] = f2bf(a.x); o.s[1] = f2bf(a.y); o.s[2] = f2bf(a.z); o.s[3] = f2bf(a.w);
    o.s[4] = f2bf(b.x); o.s[5] = f2bf(b.y); o.s[6] = f2bf(b.z); o.s[7] = f2bf(b.w);
    return o.v;
}

#define GLDS16(gp, lp)                                                        \
    __builtin_amdgcn_global_load_lds(                                         \
        (__attribute__((address_space(1))) void*)(gp),                        \
        (__attribute__((address_space(3))) void*)(lp), 16, 0, 0)

// ---------------- weight convert+transpose: Wt[n][k] = bf16(W[k][n]) --------

__global__ __launch_bounds__(256) void wconv_kernel(
    const float* __restrict__ W, bfu* __restrict__ Wt, int K, int N)
{
    __shared__ float t[32][33];
    const int bn = blockIdx.x << 5;
    const int bk = blockIdx.y << 5;
    const int tx = threadIdx.x & 31, ty = threadIdx.x >> 5;
#pragma unroll
    for (int i = 0; i < 32; i += 8)
        t[ty + i][tx] = W[(size_t)(bk + ty + i) * N + bn + tx];
    __syncthreads();
#pragma unroll
    for (int i = 0; i < 32; i += 8)
        Wt[(size_t)(bn + ty + i) * K + bk + tx] = f2bf(t[tx][ty + i]);
}

__global__ __launch_bounds__(256) void bias_concat_kernel(
    const float* __restrict__ a, const float* __restrict__ b,
    const float* __restrict__ c, float* __restrict__ o)
{
    const int t = blockIdx.x * 256 + threadIdx.x;   // grid 6*256 = 1536
    const float* src = (t < 512) ? a : (t < 1024) ? b : c;
    o[t] = src[t & 511];
}

// ---------------- LayerNorm kernels ----------------

__global__ __launch_bounds__(64) void ln1_shift_kernel(
    const float* __restrict__ x, const float* __restrict__ g,
    const float* __restrict__ be, bfu* __restrict__ out)
{
    const int ms = blockIdx.x;
    const int b = ms >> 11;
    const int ls = ms & 2047;
    const int l = (ls + 8) & 2047;
    const int c0 = threadIdx.x << 3;
    const float* xp = x + ((((size_t)(b << 11)) + l) << 9) + c0;
    F4 f0, f1; f0.v = *(const float4*)xp; f1.v = *(const float4*)(xp + 4);
    float vv[8]; float s = 0.f, sq = 0.f;
#pragma unroll
    for (int j = 0; j < 4; ++j) { vv[j] = f0.f[j]; vv[4 + j] = f1.f[j]; }
#pragma unroll
    for (int j = 0; j < 8; ++j) { s += vv[j]; sq += vv[j] * vv[j]; }
#pragma unroll
    for (int o = 32; o > 0; o >>= 1) { s += __shfl_xor(s, o); sq += __shfl_xor(sq, o); }
    const float mean = s * (1.f / 512.f);
    float var = sq * (1.f / 512.f) - mean * mean;
    var = fmaxf(var, 0.f);
    const float rstd = rsqrtf(var + 1e-12f);
    F4 g0, g1v, b0, b1;
    g0.v = *(const float4*)(g + c0);  g1v.v = *(const float4*)(g + c0 + 4);
    b0.v = *(const float4*)(be + c0); b1.v = *(const float4*)(be + c0 + 4);
    U8 o8;
#pragma unroll
    for (int j = 0; j < 4; ++j) {
        o8.s[j]     = f2bf((vv[j]     - mean) * rstd * g0.f[j]  + b0.f[j]);
        o8.s[4 + j] = f2bf((vv[4 + j] - mean) * rstd * g1v.f[j] + b1.f[j]);
    }
    *(uint4*)(out + (((size_t)ms) << 9) + c0) = o8.v;
}

__global__ __launch_bounds__(64) void ln2_kernel(
    const bfu* __restrict__ x1, const float* __restrict__ g,
    const float* __restrict__ be, bfu* __restrict__ out)
{
    const int ms = blockIdx.x;
    const int c0 = threadIdx.x << 3;
    U8 u; u.v = *(const uint4*)(x1 + (((size_t)ms) << 9) + c0);
    float vv[8]; float s = 0.f, sq = 0.f;
#pragma unroll
    for (int j = 0; j < 8; ++j) { float f = bf2f(u.s[j]); vv[j] = f; s += f; sq += f * f; }
#pragma unroll
    for (int o = 32; o > 0; o >>= 1) { s += __shfl_xor(s, o); sq += __shfl_xor(sq, o); }
    const float mean = s * (1.f / 512.f);
    float var = sq * (1.f / 512.f) - mean * mean;
    var = fmaxf(var, 0.f);
    const float rstd = rsqrtf(var + 1e-12f);
    F4 g0, g1v, b0, b1;
    g0.v = *(const float4*)(g + c0);  g1v.v = *(const float4*)(g + c0 + 4);
    b0.v = *(const float4*)(be + c0); b1.v = *(const float4*)(be + c0 + 4);
    U8 o8;
#pragma unroll
    for (int j = 0; j < 4; ++j) {
        o8.s[j]     = f2bf((vv[j]     - mean) * rstd * g0.f[j]  + b0.f[j]);
        o8.s[4 + j] = f2bf((vv[4 + j] - mean) * rstd * g1v.f[j] + b1.f[j]);
    }
    *(uint4*)(out + (((size_t)ms) << 9) + c0) = o8.v;
}

// ---------------- MFMA GEMM ----------------
// 128x128 tile, BK=32, 4 waves (2x2), wave tile 64x64 = 4x4 MFMA 16x16x32.
// LDS: As[m][k] / Bs[n][k] row-major 64B rows (direct coalesced copy).
// Staging issue a=w*2+p: lane l -> row a*16+(l>>2), kchunk (l&3)*8; LDS dst =
// base + a*1024B + l*16B (wave-uniform + lane*16 as GLDS requires).
// Bias is preloaded into acc. Epilogue stages fp32 tile in per-wave LDS, then
// coalesced 16B stores (wave-synchronous: DS ops in-order per wave).
// EPI 0: Ob=bf16(Y)  1: Ob=bf16(relu Y)
// EPI 2: Ob[unshifted] = bf16(xres + Y*mp)   3: Ofl = bf2f(prevb) + Y

template<int EPI>
__global__ __launch_bounds__(256) void mgemm(
    const bfu* __restrict__ X, const bfu* __restrict__ Wt,
    const float* __restrict__ bias,
    bfu* Ob, float* Ofl,
    const float* __restrict__ xres, const bfu* __restrict__ prevb,
    const float* __restrict__ maskpad,
    int M, int N, int K)
{
    __shared__ bfu As[4096];           // 8 KiB, [m][k] rows of 64B
    __shared__ bfu Bs[4096];           // 8 KiB, [n][k]
    __shared__ float epi[4][16][68];   // per-wave epilogue staging (17 KiB)
    const int t = threadIdx.x;
    const int lane = t & 63;
    const int w = t >> 6;
    const int wm = w >> 1, wn = w & 1;
    const int row0 = blockIdx.y << 7;
    const int col0 = blockIdx.x << 7;
    const int q = lane >> 4, l15 = lane & 15;

    // coalesced staging pointers
    const int srow = (w << 5) + (lane >> 2);        // 0..127
    const int skc = (lane & 3) << 3;                // k chunk 0/8/16/24
    const bfu* gA0 = X  + (size_t)(row0 + srow) * K + skc;
    const bfu* gA1 = gA0 + (size_t)16 * K;
    const bfu* gB0 = Wt + (size_t)(col0 + srow) * K + skc;
    const bfu* gB1 = gB0 + (size_t)16 * K;
    bfu* lA0 = As + (w << 10) + (lane << 3);
    bfu* lA1 = lA0 + 512;
    bfu* lB0 = Bs + (w << 10) + (lane << 3);
    bfu* lB1 = lB0 + 512;

    // bias preloaded into accumulators
    f32x4 acc[4][4];
    float bv[4];
#pragma unroll
    for (int j = 0; j < 4; ++j) bv[j] = bias[col0 + (wn << 6) + (j << 4) + l15];
#pragma unroll
    for (int i = 0; i < 4; ++i)
#pragma unroll
        for (int j = 0; j < 4; ++j) {
            acc[i][j][0] = bv[j]; acc[i][j][1] = bv[j];
            acc[i][j][2] = bv[j]; acc[i][j][3] = bv[j];
        }

    for (int k0 = 0; k0 < K; k0 += 32) {
        __syncthreads();
        GLDS16(gA0, lA0);
        GLDS16(gA1, lA1);
        GLDS16(gB0, lB0);
        GLDS16(gB1, lB1);
        gA0 += 32; gA1 += 32; gB0 += 32; gB1 += 32;
        __syncthreads();
        ABFrag af[4], bfr[4];
#pragma unroll
        for (int i = 0; i < 4; ++i)
            af[i].u = *(const uint4*)(As + ((((wm << 6) + (i << 4) + l15) << 5) + (q << 3)));
#pragma unroll
        for (int j = 0; j < 4; ++j)
            bfr[j].u = *(const uint4*)(Bs + ((((wn << 6) + (j << 4) + l15) << 5) + (q << 3)));
#pragma unroll
        for (int i = 0; i < 4; ++i)
#pragma unroll
            for (int j = 0; j < 4; ++j)
                acc[i][j] = __builtin_amdgcn_mfma_f32_16x16x32_bf16(
                    af[i].f, bfr[j].f, acc[i][j], 0, 0, 0);
    }

    // epilogue: stage 16x64 fp32 per wave, store coalesced
    const int c8 = (lane & 7) << 3;                 // col chunk in wave tile
    const int r8 = lane >> 3;                       // 0..7
    const int colg = col0 + (wn << 6) + c8;         // global col of chunk
#pragma unroll
    for (int i = 0; i < 4; ++i) {
#pragma unroll
        for (int j = 0; j < 4; ++j)
#pragma unroll
            for (int r = 0; r < 4; ++r) {
                float y = acc[i][j][r];
                if (EPI == 1) y = fmaxf(y, 0.f);
                epi[w][(q << 2) + r][(j << 4) + l15] = y;
            }
        __builtin_amdgcn_wave_barrier();
#pragma unroll
        for (int h = 0; h < 2; ++h) {
            const int rr = r8 + (h << 3);
            F4 f0, f1;
            f0.v = *(const float4*)&epi[w][rr][c8];
            f1.v = *(const float4*)&epi[w][rr][c8 + 4];
            const int row_out = row0 + (wm << 6) + (i << 4) + rr;
            if (EPI == 0 || EPI == 1) {
                *(uint4*)(Ob + (size_t)row_out * N + colg) = pack8(f0.v, f1.v);
            } else if (EPI == 2) {
                const int bb = row_out >> 11;
                const int ls = row_out & 2047;
                const int l = (ls + 8) & 2047;      // reverse shift
                const float mp = maskpad[(bb << 11) + l];
                const size_t dst = ((size_t)(bb << 11) + l) * (size_t)N + colg;
                F4 x0, x1v;
                x0.v = *(const float4*)(xres + dst);
                x1v.v = *(const float4*)(xres + dst + 4);
                F4 o0, o1;
#pragma unroll
                for (int jj = 0; jj < 4; ++jj) {
                    o0.f[jj] = x0.f[jj]  + f0.f[jj] * mp;
                    o1.f[jj] = x1v.f[jj] + f1.f[jj] * mp;
                }
                *(uint4*)(Ob + dst) = pack8(o0.v, o1.v);
            } else { // EPI 3
                const size_t dst = (size_t)row_out * N + colg;
                U8 pb; pb.v = *(const uint4*)(prevb + dst);
                F4 o0, o1;
#pragma unroll
                for (int jj = 0; jj < 4; ++jj) {
                    o0.f[jj] = bf2f(pb.s[jj])     + f0.f[jj];
                    o1.f[jj] = bf2f(pb.s[4 + jj]) + f1.f[jj];
                }
                *(float4*)(Ofl + dst) = o0.v;
                *(float4*)(Ofl + dst + 4) = o1.v;
            }
        }
        __builtin_amdgcn_wave_barrier();
    }
}

// ---------------- Windowed attention (qkv packed, stride 1536) --------------

__global__ __launch_bounds__(256) void attn_kernel(
    const bfu* __restrict__ qkv, const float* __restrict__ mpad,
    bfu* __restrict__ out)
{
    __shared__ float qs[16][129];
    __shared__ float ks[16][129];
    __shared__ float vs[16][129];
    __shared__ float ps[16][17];
    const int t = threadIdx.x;
    const int wg = blockIdx.x;
    const int h = blockIdx.y;
    const int b = wg >> 7;
    const int w = wg & 127;
    const int li = t >> 4;
    const int d0 = (t & 15) << 3;
    const size_t bi = (((size_t)wg << 4) + li) * 1536 + (h << 7) + d0;
    U8 uq, uk, uv;
    uq.v = *(const uint4*)(qkv + bi);
    uk.v = *(const uint4*)(qkv + bi + 512);
    uv.v = *(const uint4*)(qkv + bi + 1024);
#pragma unroll
    for (int j = 0; j < 8; ++j) {
        qs[li][d0 + j] = bf2f(uq.s[j]);
        ks[li][d0 + j] = bf2f(uk.s[j]);
        vs[li][d0 + j] = bf2f(uv.s[j]);
    }
    __syncthreads();
    const int qi = li, ki = t & 15;
    float s = 0.f;
#pragma unroll 8
    for (int d = 0; d < 128; ++d) s += qs[qi][d] * ks[ki][d];
    s *= 0.088388347648318447f;
    const bool lastw = (w == 127);
    if (lastw ? (qi >= 8 && ki >= 8) : (qi < 7 && ki >= 8)) s -= 100.f;
    const int lkey = ((w << 4) + ki + 8) & 2047;
    const bool valid = mpad[(b << 11) + lkey] > 0.f;
    if (!valid) s = -1e30f;
    float mx = s;
#pragma unroll
    for (int o = 8; o > 0; o >>= 1) mx = fmaxf(mx, __shfl_xor(mx, o, 16));
    float e = __expf(s - mx);
    float sum = e;
#pragma unroll
    for (int o = 8; o > 0; o >>= 1) sum += __shfl_xor(sum, o, 16);
    float p = e / sum;
    if (!valid) p = 0.f;
    ps[qi][ki] = p;
    __syncthreads();
    float o_[8];
#pragma unroll
    for (int j = 0; j < 8; ++j) o_[j] = 0.f;
#pragma unroll
    for (int kk = 0; kk < 16; ++kk) {
        const float pw = ps[li][kk];
#pragma unroll
        for (int j = 0; j < 8; ++j) o_[j] += pw * vs[kk][d0 + j];
    }
    U8 o8;
#pragma unroll
    for (int j = 0; j < 8; ++j) o8.s[j] = f2bf(o_[j]);
    *(uint4*)(out + (((size_t)wg << 4) + li) * 512 + (h << 7) + d0) = o8.v;
}

// ---------------- Launch ----------------

extern "C" void kernel_launch(void* const* d_in, const int* in_sizes, int n_in,
                              void* d_out, int out_size, void* d_ws, size_t ws_size,
                              hipStream_t stream)
{
    const float* x    = (const float*)d_in[0];
    const float* mpad = (const float*)d_in[3];
    const float* Wq = (const float*)d_in[4];  const float* bq = (const float*)d_in[5];
    const float* Wk = (const float*)d_in[6];  const float* bk = (const float*)d_in[7];
    const float* Wv = (const float*)d_in[8];  const float* bv = (const float*)d_in[9];
    const float* Wo = (const float*)d_in[10]; const float* bo = (const float*)d_in[11];
    const float* g1 = (const float*)d_in[12]; const float* be1 = (const float*)d_in[13];
    const float* g2 = (const float*)d_in[14]; const float* be2 = (const float*)d_in[15];
    const float* W1 = (const float*)d_in[16]; const float* bf1 = (const float*)d_in[17];
    const float* W2 = (const float*)d_in[18]; const float* bf2 = (const float*)d_in[19];
    float* out = (float*)d_out;

    char* p = (char*)d_ws;
    const size_t MB = (size_t)1 << 20;
    bfu* xn_s = (bfu*)p;                     // @0; later att
    bfu* att  = xn_s;
    bfu* qkv  = (bfu*)(p + 32 * MB);         // 96 MiB, stride 1536
    bfu* x1   = qkv;                         // @32M after attn
    bfu* W1t  = (bfu*)(p + 64 * MB);         // 2 MiB
    bfu* W2t  = (bfu*)(p + 66 * MB);         // 2 MiB
    bfu* xn2  = (bfu*)(p + 96 * MB);         // 32 MiB
    bfu* hreg = (bfu*)(p + 128 * MB);        // 128 MiB; head holds Wqkvt/Wot early
    bfu* Wqkvt = hreg;                       // 1536*512*2 = 1.5 MiB
    bfu* Wot   = hreg + 1536 * 512;          // 0.5 MiB
    float* bqkv = (float*)(hreg + 2048 * 512);  // 6 KiB

    const int M = 32768;
    dim3 blk(256);

    // pack weights/bias
    wconv_kernel<<<dim3(16, 16), blk, 0, stream>>>(Wq, Wqkvt, 512, 512);
    wconv_kernel<<<dim3(16, 16), blk, 0, stream>>>(Wk, Wqkvt + 512 * 512, 512, 512);
    wconv_kernel<<<dim3(16, 16), blk, 0, stream>>>(Wv, Wqkvt + 1024 * 512, 512, 512);
    wconv_kernel<<<dim3(16, 16), blk, 0, stream>>>(Wo, Wot, 512, 512);
    bias_concat_kernel<<<dim3(6), blk, 0, stream>>>(bq, bk, bv, bqkv);

    ln1_shift_kernel<<<32768, 64, 0, stream>>>(x, g1, be1, xn_s);

    // fused QKV: [32768 x 1536]
    mgemm<0><<<dim3(12, 256), blk, 0, stream>>>(xn_s, Wqkvt, bqkv, qkv, nullptr, nullptr, nullptr, nullptr, M, 1536, 512);

    attn_kernel<<<dim3(2048, 4), blk, 0, stream>>>(qkv, mpad, att);

    // FFN weights into dead qkv region
    wconv_kernel<<<dim3(64, 16), blk, 0, stream>>>(W1, W1t, 512, 2048);
    wconv_kernel<<<dim3(16, 64), blk, 0, stream>>>(W2, W2t, 2048, 512);

    mgemm<2><<<dim3(4, 256), blk, 0, stream>>>(att, Wot, bo, x1, nullptr, x, nullptr, mpad, M, 512, 512);

    ln2_kernel<<<32768, 64, 0, stream>>>(x1, g2, be2, xn2);

    mgemm<1><<<dim3(16, 256), blk, 0, stream>>>(xn2, W1t, bf1, hreg, nullptr, nullptr, nullptr, nullptr, M, 2048, 512);
    mgemm<3><<<dim3(4, 256), blk, 0, stream>>>(hreg, W2t, bf2, nullptr, out, nullptr, x1, nullptr, M, 512, 2048);
}

// Round 6
// 626.942 us; speedup vs baseline: 3.8614x; 1.0035x over previous
//
#include <hip/hip_runtime.h>
#include <stdint.h>

// SChunkTransformerEncoderLayer: B=16, L=2048, C=512, HEADS=4, DK=128,
// CHUNK=16, nW=128, SHIFT=8. fp32 I/O, bf16 internal, fp32 accum.
// MFMA 16x16x32 bf16 GEMMs; coalesced global_load_lds staging with
// XOR-swizzled LDS chunk layout (conflict-free frag reads, R5 post-mortem).
//
// Workspace (256 MiB):
//   @0    : xn_s (32M)  -> att (32M)
//   @32M  : qkv (96M, stride 1536) -> x1@32M / W1t@64M / W2t@66M / xn2@96M
//   @128M : Wqkvt(1.5M)+Wot(0.5M)+bqkv(6K) -> h (128M)

typedef unsigned short bfu;

using bf16x8 = __attribute__((ext_vector_type(8))) __bf16;
using f32x4  = __attribute__((ext_vector_type(4))) float;

union U8 { uint4 v; unsigned short s[8]; };
union F4 { float4 v; float f[4]; };
union ABFrag { uint4 u; bf16x8 f; };

__device__ __forceinline__ float bf2f(unsigned short u) {
    union { uint32_t i; float f; } c; c.i = ((uint32_t)u) << 16; return c.f;
}
__device__ __forceinline__ unsigned short f2bf(float f) {
    union { float f; uint32_t i; } c; c.f = f;
    uint32_t x = c.i;
    return (unsigned short)((x + 0x7FFFu + ((x >> 16) & 1u)) >> 16);
}
__device__ __forceinline__ uint4 pack8(float4 a, float4 b) {
    U8 o;
    o.s[0] = f2bf(a.x); o.s[1] = f2bf(a.y); o.s[2] = f2bf(a.z); o.s[3] = f2bf(a.w);
    o.s[4] = f2bf(b.x); o.s[5] = f2bf(b.y); o.s[6] = f2bf(b.z); o.s[7] = f2bf(b.w);
    return o.v;
}

#define GLDS16(gp, lp)                                                        \
    __builtin_amdgcn_global_load_lds(                                         \
        (__attribute__((address_space(1))) void*)(gp),                        \
        (__attribute__((address_space(3))) void*)(lp), 16, 0, 0)

// ---------------- weight convert+transpose: Wt[n][k] = bf16(W[k][n]) --------

__global__ __launch_bounds__(256) void wconv_kernel(
    const float* __restrict__ W, bfu* __restrict__ Wt, int K, int N)
{
    __shared__ float t[32][33];
    const int bn = blockIdx.x << 5;
    const int bk = blockIdx.y << 5;
    const int tx = threadIdx.x & 31, ty = threadIdx.x >> 5;
#pragma unroll
    for (int i = 0; i < 32; i += 8)
        t[ty + i][tx] = W[(size_t)(bk + ty + i) * N + bn + tx];
    __syncthreads();
#pragma unroll
    for (int i = 0; i < 32; i += 8)
        Wt[(size_t)(bn + ty + i) * K + bk + tx] = f2bf(t[tx][ty + i]);
}

__global__ __launch_bounds__(256) void bias_concat_kernel(
    const float* __restrict__ a, const float* __restrict__ b,
    const float* __restrict__ c, float* __restrict__ o)
{
    const int t = blockIdx.x * 256 + threadIdx.x;   // grid 6*256 = 1536
    const float* src = (t < 512) ? a : (t < 1024) ? b : c;
    o[t] = src[t & 511];
}

// ---------------- LayerNorm kernels ----------------

__global__ __launch_bounds__(64) void ln1_shift_kernel(
    const float* __restrict__ x, const float* __restrict__ g,
    const float* __restrict__ be, bfu* __restrict__ out)
{
    const int ms = blockIdx.x;
    const int b = ms >> 11;
    const int ls = ms & 2047;
    const int l = (ls + 8) & 2047;
    const int c0 = threadIdx.x << 3;
    const float* xp = x + ((((size_t)(b << 11)) + l) << 9) + c0;
    F4 f0, f1; f0.v = *(const float4*)xp; f1.v = *(const float4*)(xp + 4);
    float vv[8]; float s = 0.f, sq = 0.f;
#pragma unroll
    for (int j = 0; j < 4; ++j) { vv[j] = f0.f[j]; vv[4 + j] = f1.f[j]; }
#pragma unroll
    for (int j = 0; j < 8; ++j) { s += vv[j]; sq += vv[j] * vv[j]; }
#pragma unroll
    for (int o = 32; o > 0; o >>= 1) { s += __shfl_xor(s, o); sq += __shfl_xor(sq, o); }
    const float mean = s * (1.f / 512.f);
    float var = sq * (1.f / 512.f) - mean * mean;
    var = fmaxf(var, 0.f);
    const float rstd = rsqrtf(var + 1e-12f);
    F4 g0, g1v, b0, b1;
    g0.v = *(const float4*)(g + c0);  g1v.v = *(const float4*)(g + c0 + 4);
    b0.v = *(const float4*)(be + c0); b1.v = *(const float4*)(be + c0 + 4);
    U8 o8;
#pragma unroll
    for (int j = 0; j < 4; ++j) {
        o8.s[j]     = f2bf((vv[j]     - mean) * rstd * g0.f[j]  + b0.f[j]);
        o8.s[4 + j] = f2bf((vv[4 + j] - mean) * rstd * g1v.f[j] + b1.f[j]);
    }
    *(uint4*)(out + (((size_t)ms) << 9) + c0) = o8.v;
}

__global__ __launch_bounds__(64) void ln2_kernel(
    const bfu* __restrict__ x1, const float* __restrict__ g,
    const float* __restrict__ be, bfu* __restrict__ out)
{
    const int ms = blockIdx.x;
    const int c0 = threadIdx.x << 3;
    U8 u; u.v = *(const uint4*)(x1 + (((size_t)ms) << 9) + c0);
    float vv[8]; float s = 0.f, sq = 0.f;
#pragma unroll
    for (int j = 0; j < 8; ++j) { float f = bf2f(u.s[j]); vv[j] = f; s += f; sq += f * f; }
#pragma unroll
    for (int o = 32; o > 0; o >>= 1) { s += __shfl_xor(s, o); sq += __shfl_xor(sq, o); }
    const float mean = s * (1.f / 512.f);
    float var = sq * (1.f / 512.f) - mean * mean;
    var = fmaxf(var, 0.f);
    const float rstd = rsqrtf(var + 1e-12f);
    F4 g0, g1v, b0, b1;
    g0.v = *(const float4*)(g + c0);  g1v.v = *(const float4*)(g + c0 + 4);
    b0.v = *(const float4*)(be + c0); b1.v = *(const float4*)(be + c0 + 4);
    U8 o8;
#pragma unroll
    for (int j = 0; j < 4; ++j) {
        o8.s[j]     = f2bf((vv[j]     - mean) * rstd * g0.f[j]  + b0.f[j]);
        o8.s[4 + j] = f2bf((vv[4 + j] - mean) * rstd * g1v.f[j] + b1.f[j]);
    }
    *(uint4*)(out + (((size_t)ms) << 9) + c0) = o8.v;
}

// ---------------- MFMA GEMM ----------------
// 128x128 tile, BK=32, 4 waves (2x2), wave tile 64x64 = 4x4 MFMA 16x16x32.
// LDS: XOR-swizzled chunks. 16B chunk (m, c) at chunk-index m*4 + (c ^ ((m>>2)&3)).
//   Staging issue a (=2w,2w+1): lane -> global row a*16+(lane>>2),
//   chunk c=(lane&3)^((lane>>4)&3); LDS dst = base + a*1024B + lane*16B.
//   Frag read (m = wm*64+i*16+l15, chunk q): offset = (m*4 + (q^(l15>>2)))*16B
//   -> bank-quad (l15&1)*4 + (q^(l15>>2)): 2-way max (free).
// Epilogue LDS aliases As/Bs (union via char buffer, one extra barrier).
// EPI 0: Ob=bf16(Y)  1: Ob=bf16(relu Y)
// EPI 2: Ob[unshifted] = bf16(xres + Y*mp)   3: Ofl = bf2f(prevb) + Y

template<int EPI>
__global__ __launch_bounds__(256) void mgemm(
    const bfu* __restrict__ X, const bfu* __restrict__ Wt,
    const float* __restrict__ bias,
    bfu* Ob, float* Ofl,
    const float* __restrict__ xres, const bfu* __restrict__ prevb,
    const float* __restrict__ maskpad,
    int M, int N, int K)
{
    __shared__ __align__(16) char smem[17408];   // max(As+Bs 16K, epi 17.4K)
    bfu* As = (bfu*)smem;                        // 8 KiB
    bfu* Bs = (bfu*)(smem + 8192);               // 8 KiB
    float* epi = (float*)smem;                   // [4][16][68] after K-loop

    const int t = threadIdx.x;
    const int lane = t & 63;
    const int w = t >> 6;
    const int wm = w >> 1, wn = w & 1;
    const int row0 = blockIdx.y << 7;
    const int col0 = blockIdx.x << 7;
    const int q = lane >> 4, l15 = lane & 15;

    // coalesced swizzled staging
    const int srow = (w << 5) + (lane >> 2);                 // rows 2w*16..
    const int skc = (((lane & 3) ^ ((lane >> 4) & 3)) << 3); // swizzled k-chunk
    const bfu* gA0 = X  + (size_t)(row0 + srow) * K + skc;
    const bfu* gA1 = gA0 + (size_t)16 * K;
    const bfu* gB0 = Wt + (size_t)(col0 + srow) * K + skc;
    const bfu* gB1 = gB0 + (size_t)16 * K;
    bfu* lA0 = As + (w << 10) + (lane << 3);
    bfu* lA1 = lA0 + 512;
    bfu* lB0 = Bs + (w << 10) + (lane << 3);
    bfu* lB1 = lB0 + 512;

    // bias preloaded into accumulators
    f32x4 acc[4][4];
    float bv[4];
#pragma unroll
    for (int j = 0; j < 4; ++j) bv[j] = bias[col0 + (wn << 6) + (j << 4) + l15];
#pragma unroll
    for (int i = 0; i < 4; ++i)
#pragma unroll
        for (int j = 0; j < 4; ++j) {
            acc[i][j][0] = bv[j]; acc[i][j][1] = bv[j];
            acc[i][j][2] = bv[j]; acc[i][j][3] = bv[j];
        }

    const int sw = q ^ (l15 >> 2);   // frag-read swizzle (chunk index)
    for (int k0 = 0; k0 < K; k0 += 32) {
        __syncthreads();
        GLDS16(gA0, lA0);
        GLDS16(gA1, lA1);
        GLDS16(gB0, lB0);
        GLDS16(gB1, lB1);
        gA0 += 32; gA1 += 32; gB0 += 32; gB1 += 32;
        __syncthreads();
        ABFrag af[4], bfr[4];
#pragma unroll
        for (int i = 0; i < 4; ++i)
            af[i].u = *(const uint4*)(As + ((((wm << 6) + (i << 4) + l15) << 5) + (sw << 3)));
#pragma unroll
        for (int j = 0; j < 4; ++j)
            bfr[j].u = *(const uint4*)(Bs + ((((wn << 6) + (j << 4) + l15) << 5) + (sw << 3)));
#pragma unroll
        for (int i = 0; i < 4; ++i)
#pragma unroll
            for (int j = 0; j < 4; ++j)
                acc[i][j] = __builtin_amdgcn_mfma_f32_16x16x32_bf16(
                    af[i].f, bfr[j].f, acc[i][j], 0, 0, 0);
    }
    __syncthreads();   // As/Bs dead; epi aliases them

    // epilogue: stage 16x64 fp32 per wave, store coalesced
    float* epw = epi + w * 1088;                    // [16][68]
    const int c8 = (lane & 7) << 3;
    const int r8 = lane >> 3;
    const int colg = col0 + (wn << 6) + c8;
#pragma unroll
    for (int i = 0; i < 4; ++i) {
#pragma unroll
        for (int j = 0; j < 4; ++j)
#pragma unroll
            for (int r = 0; r < 4; ++r) {
                float y = acc[i][j][r];
                if (EPI == 1) y = fmaxf(y, 0.f);
                epw[((q << 2) + r) * 68 + (j << 4) + l15] = y;
            }
        __builtin_amdgcn_wave_barrier();
#pragma unroll
        for (int h = 0; h < 2; ++h) {
            const int rr = r8 + (h << 3);
            F4 f0, f1;
            f0.v = *(const float4*)&epw[rr * 68 + c8];
            f1.v = *(const float4*)&epw[rr * 68 + c8 + 4];
            const int row_out = row0 + (wm << 6) + (i << 4) + rr;
            if (EPI == 0 || EPI == 1) {
                *(uint4*)(Ob + (size_t)row_out * N + colg) = pack8(f0.v, f1.v);
            } else if (EPI == 2) {
                const int bb = row_out >> 11;
                const int ls = row_out & 2047;
                const int l = (ls + 8) & 2047;      // reverse shift
                const float mp = maskpad[(bb << 11) + l];
                const size_t dst = ((size_t)(bb << 11) + l) * (size_t)N + colg;
                F4 x0, x1v;
                x0.v = *(const float4*)(xres + dst);
                x1v.v = *(const float4*)(xres + dst + 4);
                F4 o0, o1;
#pragma unroll
                for (int jj = 0; jj < 4; ++jj) {
                    o0.f[jj] = x0.f[jj]  + f0.f[jj] * mp;
                    o1.f[jj] = x1v.f[jj] + f1.f[jj] * mp;
                }
                *(uint4*)(Ob + dst) = pack8(o0.v, o1.v);
            } else { // EPI 3
                const size_t dst = (size_t)row_out * N + colg;
                U8 pb; pb.v = *(const uint4*)(prevb + dst);
                F4 o0, o1;
#pragma unroll
                for (int jj = 0; jj < 4; ++jj) {
                    o0.f[jj] = bf2f(pb.s[jj])     + f0.f[jj];
                    o1.f[jj] = bf2f(pb.s[4 + jj]) + f1.f[jj];
                }
                *(float4*)(Ofl + dst) = o0.v;
                *(float4*)(Ofl + dst + 4) = o1.v;
            }
        }
        __builtin_amdgcn_wave_barrier();
    }
}

// ---------------- Windowed attention (qkv packed, stride 1536) --------------

__global__ __launch_bounds__(256) void attn_kernel(
    const bfu* __restrict__ qkv, const float* __restrict__ mpad,
    bfu* __restrict__ out)
{
    __shared__ float qs[16][129];
    __shared__ float ks[16][129];
    __shared__ float vs[16][129];
    __shared__ float ps[16][17];
    const int t = threadIdx.x;
    const int wg = blockIdx.x;
    const int h = blockIdx.y;
    const int b = wg >> 7;
    const int w = wg & 127;
    const int li = t >> 4;
    const int d0 = (t & 15) << 3;
    const size_t bi = (((size_t)wg << 4) + li) * 1536 + (h << 7) + d0;
    U8 uq, uk, uv;
    uq.v = *(const uint4*)(qkv + bi);
    uk.v = *(const uint4*)(qkv + bi + 512);
    uv.v = *(const uint4*)(qkv + bi + 1024);
#pragma unroll
    for (int j = 0; j < 8; ++j) {
        qs[li][d0 + j] = bf2f(uq.s[j]);
        ks[li][d0 + j] = bf2f(uk.s[j]);
        vs[li][d0 + j] = bf2f(uv.s[j]);
    }
    __syncthreads();
    const int qi = li, ki = t & 15;
    float s = 0.f;
#pragma unroll 8
    for (int d = 0; d < 128; ++d) s += qs[qi][d] * ks[ki][d];
    s *= 0.088388347648318447f;
    const bool lastw = (w == 127);
    if (lastw ? (qi >= 8 && ki >= 8) : (qi < 7 && ki >= 8)) s -= 100.f;
    const int lkey = ((w << 4) + ki + 8) & 2047;
    const bool valid = mpad[(b << 11) + lkey] > 0.f;
    if (!valid) s = -1e30f;
    float mx = s;
#pragma unroll
    for (int o = 8; o > 0; o >>= 1) mx = fmaxf(mx, __shfl_xor(mx, o, 16));
    float e = __expf(s - mx);
    float sum = e;
#pragma unroll
    for (int o = 8; o > 0; o >>= 1) sum += __shfl_xor(sum, o, 16);
    float p = e / sum;
    if (!valid) p = 0.f;
    ps[qi][ki] = p;
    __syncthreads();
    float o_[8];
#pragma unroll
    for (int j = 0; j < 8; ++j) o_[j] = 0.f;
#pragma unroll
    for (int kk = 0; kk < 16; ++kk) {
        const float pw = ps[li][kk];
#pragma unroll
        for (int j = 0; j < 8; ++j) o_[j] += pw * vs[kk][d0 + j];
    }
    U8 o8;
#pragma unroll
    for (int j = 0; j < 8; ++j) o8.s[j] = f2bf(o_[j]);
    *(uint4*)(out + (((size_t)wg << 4) + li) * 512 + (h << 7) + d0) = o8.v;
}

// ---------------- Launch ----------------

extern "C" void kernel_launch(void* const* d_in, const int* in_sizes, int n_in,
                              void* d_out, int out_size, void* d_ws, size_t ws_size,
                              hipStream_t stream)
{
    const float* x    = (const float*)d_in[0];
    const float* mpad = (const float*)d_in[3];
    const float* Wq = (const float*)d_in[4];  const float* bq = (const float*)d_in[5];
    const float* Wk = (const float*)d_in[6];  const float* bk = (const float*)d_in[7];
    const float* Wv = (const float*)d_in[8];  const float* bv = (const float*)d_in[9];
    const float* Wo = (const float*)d_in[10]; const float* bo = (const float*)d_in[11];
    const float* g1 = (const float*)d_in[12]; const float* be1 = (const float*)d_in[13];
    const float* g2 = (const float*)d_in[14]; const float* be2 = (const float*)d_in[15];
    const float* W1 = (const float*)d_in[16]; const float* bf1 = (const float*)d_in[17];
    const float* W2 = (const float*)d_in[18]; const float* bf2 = (const float*)d_in[19];
    float* out = (float*)d_out;

    char* p = (char*)d_ws;
    const size_t MB = (size_t)1 << 20;
    bfu* xn_s = (bfu*)p;                     // @0; later att
    bfu* att  = xn_s;
    bfu* qkv  = (bfu*)(p + 32 * MB);         // 96 MiB, stride 1536
    bfu* x1   = qkv;                         // @32M after attn
    bfu* W1t  = (bfu*)(p + 64 * MB);         // 2 MiB
    bfu* W2t  = (bfu*)(p + 66 * MB);         // 2 MiB
    bfu* xn2  = (bfu*)(p + 96 * MB);         // 32 MiB
    bfu* hreg = (bfu*)(p + 128 * MB);        // 128 MiB; head holds Wqkvt/Wot early
    bfu* Wqkvt = hreg;                       // 1.5 MiB
    bfu* Wot   = hreg + 1536 * 512;          // 0.5 MiB
    float* bqkv = (float*)(hreg + 2048 * 512);  // 6 KiB

    const int M = 32768;
    dim3 blk(256);

    // pack weights/bias
    wconv_kernel<<<dim3(16, 16), blk, 0, stream>>>(Wq, Wqkvt, 512, 512);
    wconv_kernel<<<dim3(16, 16), blk, 0, stream>>>(Wk, Wqkvt + 512 * 512, 512, 512);
    wconv_kernel<<<dim3(16, 16), blk, 0, stream>>>(Wv, Wqkvt + 1024 * 512, 512, 512);
    wconv_kernel<<<dim3(16, 16), blk, 0, stream>>>(Wo, Wot, 512, 512);
    bias_concat_kernel<<<dim3(6), blk, 0, stream>>>(bq, bk, bv, bqkv);

    ln1_shift_kernel<<<32768, 64, 0, stream>>>(x, g1, be1, xn_s);

    // fused QKV: [32768 x 1536]
    mgemm<0><<<dim3(12, 256), blk, 0, stream>>>(xn_s, Wqkvt, bqkv, qkv, nullptr, nullptr, nullptr, nullptr, M, 1536, 512);

    attn_kernel<<<dim3(2048, 4), blk, 0, stream>>>(qkv, mpad, att);

    // FFN weights into dead qkv region
    wconv_kernel<<<dim3(64, 16), blk, 0, stream>>>(W1, W1t, 512, 2048);
    wconv_kernel<<<dim3(16, 64), blk, 0, stream>>>(W2, W2t, 2048, 512);

    mgemm<2><<<dim3(4, 256), blk, 0, stream>>>(att, Wot, bo, x1, nullptr, x, nullptr, mpad, M, 512, 512);

    ln2_kernel<<<32768, 64, 0, stream>>>(x1, g2, be2, xn2);

    mgemm<1><<<dim3(16, 256), blk, 0, stream>>>(xn2, W1t, bf1, hreg, nullptr, nullptr, nullptr, nullptr, M, 2048, 512);
    mgemm<3><<<dim3(4, 256), blk, 0, stream>>>(hreg, W2t, bf2, nullptr, out, nullptr, x1, nullptr, M, 512, 2048);
}